// Round 1
// baseline (631.460 us; speedup 1.0000x reference)
//
#include <hip/hip_runtime.h>
#include <hip/hip_bf16.h>
#include <math.h>

#define M 4096
#define NSAMP 8192
#define K 128
#define VOCABF 1000000.0f

typedef __bf16 bf16x8 __attribute__((ext_vector_type(8)));
typedef float f32x16 __attribute__((ext_vector_type(16)));
typedef unsigned short u16x8 __attribute__((ext_vector_type(8)));

// RNE float->bf16 (inputs are finite normals; NaN path not needed)
__device__ inline unsigned short f2bf(float f) {
    unsigned int u = __float_as_uint(f);
    return (unsigned short)((u + 0x7FFFu + ((u >> 16) & 1u)) >> 16);
}

__device__ inline u16x8 pack8(float4 f0, float4 f1) {
    u16x8 v;
    v[0] = f2bf(f0.x); v[1] = f2bf(f0.y); v[2] = f2bf(f0.z); v[3] = f2bf(f0.w);
    v[4] = f2bf(f1.x); v[5] = f2bf(f1.y); v[6] = f2bf(f1.z); v[7] = f2bf(f1.w);
    return v;
}
__device__ inline bf16x8 as_bf(u16x8 u) {
    union { u16x8 u; bf16x8 b; } cv; cv.u = u; return cv.b;
}

// ---- fused: W-gather->bf16->LDS (dbuf, XOR-swizzled) + bf16 MFMA GEMM
//      + bias/sampling correction + exp + per-row partial sums ----------
// grid (32,32): blockIdx.x -> 128-row strip, blockIdx.y -> 256-col strip.
// 4 waves, each owns 32 rows; 8 n-tiles of 32 cols, K=128 in registers (A).
// B per n-tile staged in LDS: [32 cols][128 k] bf16 = 8 KB, double-buffered.
__global__ __launch_bounds__(256, 4) void fused_gemm(
        const float* __restrict__ pred,
        const int* __restrict__ sampled,
        const float* __restrict__ W,
        const float* __restrict__ bias,
        float* __restrict__ partial,   // [32][M] write-once, no atomics
        float* __restrict__ out) {
    __shared__ __align__(16) unsigned short Bt[2][32 * K];
    __shared__ float Bc[2][32];

    const int tid  = threadIdx.x;
    const int lane = tid & 63;
    const int wid  = tid >> 6;         // 0..3: m-wave
    const int l31  = lane & 31;
    const int half = lane >> 5;        // 0/1
    const int bx = blockIdx.x, by = blockIdx.y;

    if (bx == 0 && by == 0 && tid == 0) out[0] = 0.0f;  // zero for finalize's atomics

    // ---- A fragments for all of K=128, f32->bf16 in-register (32 VGPRs) ----
    // layout: A[m = lane&31][k = (lane>>5)*8 + j], k-step stride 16
    const int mrow = bx * 128 + wid * 32 + l31;
    bf16x8 a[8];
    {
        const float* ap = pred + (size_t)mrow * K + half * 8;
#pragma unroll
        for (int ks = 0; ks < 8; ++ks) {
            float4 f0 = *(const float4*)(ap + ks * 16);
            float4 f1 = *(const float4*)(ap + ks * 16 + 4);
            a[ks] = as_bf(pack8(f0, f1));
        }
    }

    // ---- staging roles: thread = (scol 0..31, seg 0..7), 16 floats each ----
    const int scol = tid >> 3;
    const int seg  = tid & 7;
    float4 r0, r1, r2, r3; float bsv = 0.0f; int sid = 0;

    // T14 split: LOAD issues global reads early; WRITE converts + ds_writes late.
    auto LOAD = [&](int t) {
        sid = sampled[by * 256 + t * 32 + scol];
        const float4* src = (const float4*)(W + (size_t)sid * K + seg * 16);
        r0 = src[0]; r1 = src[1]; r2 = src[2]; r3 = src[3];
        if (seg == 0) bsv = bias[sid];
    };
    auto WRITE = [&](int b) {
        u16x8 lo = pack8(r0, r1), hi = pack8(r2, r3);
        // T2: XOR-swizzle byte offset within the 256 B row (16 B granules)
        const int swz = (scol & 15) << 4;
        char* rowp = (char*)&Bt[b][scol * K];
        const int o0 = seg * 32;
        *(u16x8*)(rowp + ((o0)      ^ swz)) = lo;
        *(u16x8*)(rowp + ((o0 + 16) ^ swz)) = hi;
        if (seg == 0) {
            float kk = (float)sid;
            // log(k+2)-log(k+1) as log1p(1/(k+1)): avoids f32 cancellation at k~1e6
            float q = log1pf(1.0f / (kk + 1.0f)) / logf(VOCABF + 1.0f);
            Bc[b][scol] = bsv - logf((float)NSAMP * q);
        }
    };

    float rs[16];
#pragma unroll
    for (int r = 0; r < 16; ++r) rs[r] = 0.0f;

    LOAD(0); WRITE(0);
    __syncthreads();

#pragma unroll
    for (int t = 0; t < 8; ++t) {
        const int cur = t & 1;
        if (t < 7) LOAD(t + 1);                 // issue next-tile loads (hide under MFMA)

        const float bc = Bc[cur][l31];          // bias+corr folded into C-init
        f32x16 acc;
#pragma unroll
        for (int r = 0; r < 16; ++r) acc[r] = bc;
        const char* rowp = (const char*)&Bt[cur][l31 * K];
        const int swz = (l31 & 15) << 4;
#pragma unroll
        for (int ks = 0; ks < 8; ++ks) {
            bf16x8 bf = *(const bf16x8*)(rowp + ((half * 16 + ks * 32) ^ swz));
            acc = __builtin_amdgcn_mfma_f32_32x32x16_bf16(a[ks], bf, acc, 0, 0, 0);
        }
        // logits bounded in ~[-9, +11]: exp-sum safe in f32 without max-sub
#pragma unroll
        for (int r = 0; r < 16; ++r) rs[r] += __expf(acc[r]);

        if (t < 7) WRITE((t + 1) & 1);          // drain loads, fill other buffer
        __syncthreads();
    }

    // reduce across the 32 cols (lanes of each half-wave share rows)
#pragma unroll
    for (int m = 1; m <= 16; m <<= 1) {
#pragma unroll
        for (int r = 0; r < 16; ++r) rs[r] += __shfl_xor(rs[r], m, 64);
    }
    if (l31 == 0) {
        const int rb = bx * 128 + wid * 32 + 4 * half;
#pragma unroll
        for (int r = 0; r < 16; ++r) {
            int row = rb + (r & 3) + 8 * (r >> 2);  // verified C/D row map
            partial[by * M + row] = rs[r];          // write-once: no atomic, no zero-init
        }
    }
}

// ---- finalize: true logits (f32), partial-slab sum, per-row loss, mean ----
__global__ __launch_bounds__(256) void finalize(const float* __restrict__ pred,
                                                const int* __restrict__ labels,
                                                const float* __restrict__ W,
                                                const float* __restrict__ bias,
                                                const float* __restrict__ partial,
                                                float* __restrict__ out) {
    __shared__ float part[16];
    int t = blockIdx.x * 256 + threadIdx.x;   // 16 threads per row
    int row = t >> 4, c = t & 15;
    int id = labels[row];
    const float* wp = W + (size_t)id * K + c * 8;
    const float* pp = pred + (size_t)row * K + c * 8;
    float4 w0 = *(const float4*)wp, w1 = *(const float4*)(wp + 4);
    float4 p0 = *(const float4*)pp, p1 = *(const float4*)(pp + 4);
    float d = w0.x * p0.x + w0.y * p0.y + w0.z * p0.z + w0.w * p0.w
            + w1.x * p1.x + w1.y * p1.y + w1.z * p1.z + w1.w * p1.w;
    float s = partial[c * M + row] + partial[(c + 16) * M + row];
#pragma unroll
    for (int m = 1; m <= 8; m <<= 1) {
        d += __shfl_xor(d, m, 64);
        s += __shfl_xor(s, m, 64);
    }
    if (c == 0) {
        float kk = (float)id;
        float q = log1pf(1.0f / (kk + 1.0f)) / logf(VOCABF + 1.0f);
        float tl = d + bias[id] - logf((float)NSAMP * q);
        float loss = logf(s + __expf(tl)) - tl;
        part[threadIdx.x >> 4] = loss;
    }
    __syncthreads();
    if (threadIdx.x == 0) {
        float sum = 0.0f;
#pragma unroll
        for (int i = 0; i < 16; ++i) sum += part[i];
        atomicAdd(out, sum * (1.0f / (float)M));
    }
}

extern "C" void kernel_launch(void* const* d_in, const int* in_sizes, int n_in,
                              void* d_out, int out_size, void* d_ws, size_t ws_size,
                              hipStream_t stream) {
    const float* pred    = (const float*)d_in[0];
    const int*   labels  = (const int*)d_in[1];
    const int*   sampled = (const int*)d_in[2];
    const float* W       = (const float*)d_in[3];
    const float* b       = (const float*)d_in[4];
    float* out = (float*)d_out;

    float* partial = (float*)d_ws;   // 32*4096 f32 = 512 KB

    fused_gemm<<<dim3(32, 32), 256, 0, stream>>>(pred, sampled, W, b, partial, out);
    finalize<<<256, 256, 0, stream>>>(pred, labels, W, b, partial, out);
}

// Round 2
// 597.531 us; speedup vs baseline: 1.0568x; 1.0568x over previous
//
#include <hip/hip_runtime.h>
#include <hip/hip_bf16.h>
#include <math.h>

#define M 4096
#define NSAMP 8192
#define K 128
#define VOCABF 1000000.0f

typedef __bf16 bf16x8 __attribute__((ext_vector_type(8)));
typedef float f32x16 __attribute__((ext_vector_type(16)));
typedef unsigned short u16x8 __attribute__((ext_vector_type(8)));

// RNE float->bf16 (inputs are finite normals; NaN path not needed)
__device__ inline unsigned short f2bf(float f) {
    unsigned int u = __float_as_uint(f);
    return (unsigned short)((u + 0x7FFFu + ((u >> 16) & 1u)) >> 16);
}

__device__ inline u16x8 pack8(float4 f0, float4 f1) {
    u16x8 v;
    v[0] = f2bf(f0.x); v[1] = f2bf(f0.y); v[2] = f2bf(f0.z); v[3] = f2bf(f0.w);
    v[4] = f2bf(f1.x); v[5] = f2bf(f1.y); v[6] = f2bf(f1.z); v[7] = f2bf(f1.w);
    return v;
}
__device__ inline bf16x8 as_bf(u16x8 u) {
    union { u16x8 u; bf16x8 b; } cv; cv.u = u; return cv.b;
}

// ---- prep: one-shot W-row gather -> bf16 Wsb (dedup: gather ONCE, not
//      per row-strip — round-1's fused 32x-redundant gather cost +37us),
//      bias/sampling correction, true-logit dot (inputs only), out zero. ----
// blocks [0,512):  sampled gather, 16 threads/row
// blocks [512,768): true-logit rows, 16 threads/row
__global__ __launch_bounds__(256) void prep(const float* __restrict__ pred,
                                            const int* __restrict__ labels,
                                            const int* __restrict__ sampled,
                                            const float* __restrict__ W,
                                            const float* __restrict__ bias,
                                            unsigned short* __restrict__ Wsb,
                                            float* __restrict__ bcorr,
                                            float* __restrict__ tl,
                                            float* __restrict__ out) {
    const float inv_logv = 1.0f / logf(VOCABF + 1.0f);
    const int bx = blockIdx.x;
    if (bx < 512) {
        int t = bx * 256 + threadIdx.x;
        if (t == 0) out[0] = 0.0f;            // finalize atomics accumulate here
        int s = t >> 4, c = t & 15;
        int id = sampled[s];
        const float* src = W + (size_t)id * K + c * 8;
        float4 f0 = *(const float4*)src;
        float4 f1 = *(const float4*)(src + 4);
        *(u16x8*)(Wsb + s * K + c * 8) = pack8(f0, f1);
        if (c == 0) {
            float kk = (float)id;
            // log(k+2)-log(k+1) as log1p(1/(k+1)): avoids f32 cancellation at k~1e6
            float q = log1pf(1.0f / (kk + 1.0f)) * inv_logv;
            bcorr[s] = bias[id] - logf((float)NSAMP * q);
        }
    } else {
        int t = (bx - 512) * 256 + threadIdx.x;
        int row = t >> 4, c = t & 15;
        int id = labels[row];
        const float* wp = W + (size_t)id * K + c * 8;
        const float* pp = pred + (size_t)row * K + c * 8;
        float4 w0 = *(const float4*)wp, w1 = *(const float4*)(wp + 4);
        float4 p0 = *(const float4*)pp, p1 = *(const float4*)(pp + 4);
        float d = w0.x * p0.x + w0.y * p0.y + w0.z * p0.z + w0.w * p0.w
                + w1.x * p1.x + w1.y * p1.y + w1.z * p1.z + w1.w * p1.w;
#pragma unroll
        for (int m = 1; m <= 8; m <<= 1) d += __shfl_xor(d, m, 64);
        if (c == 0) {
            float kk = (float)id;
            float q = log1pf(1.0f / (kk + 1.0f)) * inv_logv;
            tl[row] = d + bias[id] - logf((float)NSAMP * q);
        }
    }
}

// ---- main: bf16 MFMA GEMM + exp + per-row partial sums -----------------
// grid (32,32): blockIdx.x -> 128-row strip, blockIdx.y -> 256-col strip
// 4 waves: each wave owns 32 rows, iterates 8 n-tiles of 32 cols, K=128.
// A built in-register from f32 pred (no Pb round-trip); B read directly
// from L2-resident bf16 Wsb (2 MB); partial slabs: no atomics, no zeroing.
__global__ __launch_bounds__(256, 4) void main_gemm(
        const float* __restrict__ pred,
        const unsigned short* __restrict__ Wsb,
        const float* __restrict__ bcorr,
        float* __restrict__ partial) {
    const int tid  = threadIdx.x;
    const int lane = tid & 63;
    const int wid  = tid >> 6;         // 0..3: m-wave
    const int l31  = lane & 31;
    const int half = lane >> 5;        // 0/1
    const int mrow = blockIdx.x * 128 + wid * 32 + l31;
    const int nb   = blockIdx.y * 256;

    // A fragments for all of K=128, f32->bf16 in-register (32 VGPRs)
    // layout: A[m = lane&31][k = (lane>>5)*8 + j], k-step stride 16
    bf16x8 a[8];
    {
        const float* ap = pred + (size_t)mrow * K + half * 8;
#pragma unroll
        for (int ks = 0; ks < 8; ++ks) {
            float4 f0 = *(const float4*)(ap + ks * 16);
            float4 f1 = *(const float4*)(ap + ks * 16 + 4);
            a[ks] = as_bf(pack8(f0, f1));
        }
    }

    float rs[16];
#pragma unroll
    for (int r = 0; r < 16; ++r) rs[r] = 0.0f;

#pragma unroll
    for (int t = 0; t < 8; ++t) {
        const int col = nb + t * 32 + l31;
        const float bc = bcorr[col];          // same col for all 16 acc regs
        f32x16 acc;
#pragma unroll
        for (int r = 0; r < 16; ++r) acc[r] = bc;   // bias folded into C-init
        const unsigned short* bp = Wsb + (size_t)col * K + half * 8;
#pragma unroll
        for (int ks = 0; ks < 8; ++ks) {
            bf16x8 bf = *(const bf16x8*)(bp + ks * 16);
            acc = __builtin_amdgcn_mfma_f32_32x32x16_bf16(a[ks], bf, acc, 0, 0, 0);
        }
        // logits bounded in ~[-9, +11]: exp-sum safe in f32 without max-sub
#pragma unroll
        for (int r = 0; r < 16; ++r) rs[r] += __expf(acc[r]);
    }

    // reduce across the 32 cols (lanes of each half-wave share rows)
#pragma unroll
    for (int m = 1; m <= 16; m <<= 1) {
#pragma unroll
        for (int r = 0; r < 16; ++r) rs[r] += __shfl_xor(rs[r], m, 64);
    }
    if (l31 == 0) {
        const int rb = blockIdx.x * 128 + wid * 32 + 4 * half;
#pragma unroll
        for (int r = 0; r < 16; ++r) {
            int row = rb + (r & 3) + 8 * (r >> 2);  // verified C/D row map
            partial[blockIdx.y * M + row] = rs[r];  // write-once: no atomic
        }
    }
}

// ---- finalize: sum 32 partials/row (coalesced), loss, mean -------------
__global__ __launch_bounds__(256) void finalize(const float* __restrict__ partial,
                                                const float* __restrict__ tl,
                                                float* __restrict__ out) {
    __shared__ float wsum[4];
    int row = blockIdx.x * 256 + threadIdx.x;
    float s = 0.0f;
#pragma unroll
    for (int j = 0; j < 32; ++j) s += partial[j * M + row];  // coalesced per j
    float t = tl[row];
    float loss = logf(s + __expf(t)) - t;
#pragma unroll
    for (int m = 1; m <= 32; m <<= 1) loss += __shfl_xor(loss, m, 64);
    if ((threadIdx.x & 63) == 0) wsum[threadIdx.x >> 6] = loss;
    __syncthreads();
    if (threadIdx.x == 0)
        atomicAdd(out, (wsum[0] + wsum[1] + wsum[2] + wsum[3]) * (1.0f / (float)M));
}

extern "C" void kernel_launch(void* const* d_in, const int* in_sizes, int n_in,
                              void* d_out, int out_size, void* d_ws, size_t ws_size,
                              hipStream_t stream) {
    const float* pred    = (const float*)d_in[0];
    const int*   labels  = (const int*)d_in[1];
    const int*   sampled = (const int*)d_in[2];
    const float* W       = (const float*)d_in[3];
    const float* b       = (const float*)d_in[4];
    float* out = (float*)d_out;

    char* ws = (char*)d_ws;
    unsigned short* Wsb   = (unsigned short*)ws;                         // 2 MB
    float*          bcorr = (float*)(ws + (1 << 21));                    // 32 KB
    float*          tl    = (float*)(ws + (1 << 21) + (1 << 15));        // 16 KB
    float*          part  = (float*)(ws + (1 << 21) + (1 << 15) + (1 << 14)); // 512 KB

    prep<<<768, 256, 0, stream>>>(pred, labels, sampled, W, b, Wsb, bcorr, tl, out);
    main_gemm<<<dim3(32, 32), 256, 0, stream>>>(pred, Wsb, bcorr, part);
    finalize<<<16, 256, 0, stream>>>(part, tl, out);
}